// Round 10
// baseline (96.718 us; speedup 1.0000x reference)
//
#include <hip/hip_runtime.h>

#define POOL_H 7
#define POOL_W 7
#define BINS   49
#define SR 2
#define SCALE 0.25f
#define CH 256          // channels (fixed by problem)

typedef unsigned int   u32;
typedef unsigned short u16;
typedef unsigned long long u64;
typedef float f2v __attribute__((ext_vector_type(2)));
typedef f2v uf2 __attribute__((aligned(4)));
typedef float f4  __attribute__((ext_vector_type(4)));
typedef u32  ui4 __attribute__((ext_vector_type(4)));

__device__ __forceinline__ u16 f32_to_bf16_rne(float f) {
    u32 u = __builtin_bit_cast(u32, f);
    u32 r = (u + 0x7FFFu + ((u >> 16) & 1u)) >> 16;
    return (u16)r;
}
__device__ __forceinline__ float bf16lo(u32 u) { return __builtin_bit_cast(float, u << 16); }
__device__ __forceinline__ float bf16hi(u32 u) { return __builtin_bit_cast(float, u & 0xFFFF0000u); }

// async global->LDS DMA, 16B per lane (wave: 1KB). Dest must be wave-uniform
// base; lane l lands at base + l*16 (HW rule, learn_hip m104).
__device__ __forceinline__ void gload_lds16(const float* g, float* l) {
    __builtin_amdgcn_global_load_lds(
        (const __attribute__((address_space(1))) void*)g,
        (__attribute__((address_space(3))) void*)l,
        16, 0, 0);
}

// ---------------- Pass 1: NCHW f32 -> NHWC bf16 transpose + ROI spatial sort
// Tile = 64 hw x 128 c, staged fp32 in LDS via global_load_lds width-16:
// zero VGPR round-trip, all 32 staging instrs per block in flight at once
// (the VGPR path serialized on vmcnt -> ~3.2 TB/s ceiling in r7-r9).
// LDS layout is rotation-swizzled via PRE-SWIZZLED SOURCE (m173 pattern):
//   word(c,hw) = c*64 + ((hw + 4*(c>>3)) & 63)
// -> store-phase reads (lanes span cg at fixed hw-group) hit 2 lanes/bank
//    (free), global stores stay 256B-contiguous full-line segments.
__global__ __launch_bounds__(512) void nchw_to_nhwc_bf16(
    const float* __restrict__ feat, u16* __restrict__ ft,
    const float* __restrict__ rois, int* __restrict__ perm,
    int HW, int tiles, int K, int H, int W)
{
    __shared__ __align__(16) unsigned char smem[32768];  // 32 KB -> 4 blocks/CU

    int t = threadIdx.x;

    if ((int)blockIdx.x == gridDim.x - 1) {
        // ---- ROI spatial sort (K <= 1024), 8KB of smem ----
        u64* keys = (u64*)smem;
        int bd = (int)blockDim.x;
        for (int v = t; v < 1024; v += bd) {
            u64 kv = ~0ull;
            if (v < K) {
                const float* rp = rois + (size_t)v * 5;
                int b = (int)rp[0];
                float cx = 0.5f * (rp[1] + rp[3]) * SCALE;
                float cy = 0.5f * (rp[2] + rp[4]) * SCALE;
                int qx = min(15, max(0, (int)(cx * (16.0f / (float)W))));
                int qy = min(15, max(0, (int)(cy * (16.0f / (float)H))));
                u32 m = 0;
                #pragma unroll
                for (int i = 0; i < 4; ++i)
                    m |= (((qy >> i) & 1u) << (2 * i + 1)) | (((qx >> i) & 1u) << (2 * i));
                u32 key = ((u32)b << 8) | m;
                kv = ((u64)key << 32) | (u32)v;
            }
            keys[v] = kv;
        }
        __syncthreads();
        for (int size = 2; size <= 1024; size <<= 1) {
            for (int stride = size >> 1; stride > 0; stride >>= 1) {
                for (int v = t; v < 1024; v += bd) {
                    int j = v ^ stride;
                    if (j > v) {
                        bool up = ((v & size) == 0);
                        u64 a = keys[v], bb = keys[j];
                        if ((a > bb) == up) { keys[v] = bb; keys[j] = a; }
                    }
                }
                __syncthreads();
            }
        }
        for (int v = t; v < K; v += bd)
            perm[v] = (int)(keys[v] & 0xffffffffu);
        return;
    }

    float* lf = (float*)smem;           // logical [128 c][64 hw] fp32, swizzled
    int bid   = blockIdx.x;
    int chalf = bid & 1;
    int tile  = (bid >> 1) % tiles;
    int b     = (bid >> 1) / tiles;
    int hw0   = tile * 64;

    int lane = t & 63;
    int w    = t >> 6;                  // 0..7

    // ---- async staging: 32 x gload_lds16, 4 per wave, no waits until barrier
    // instr i covers LDS rows 4i..4i+3; lane l -> row r = 4i + (l>>4),
    // 16B chunk at LDS words r*64 + 4*(l&15).. ; source hw rotated by
    // -4*(r>>3) so that word(c,hw) = c*64 + ((hw + 4*(c>>3)) & 63).
    const float* src = feat + ((size_t)b * CH + (size_t)chalf * 128) * HW + hw0;
    #pragma unroll
    for (int ii = 0; ii < 4; ++ii) {
        int i = w * 4 + ii;
        int r = 4 * i + (lane >> 4);
        int hwb = (4 * (lane & 15) - 4 * (r >> 3)) & 63;   // inverse rotation
        gload_lds16(src + (size_t)r * HW + hwb, &lf[i * 256]);
    }
    __syncthreads();    // compiler drains vmcnt(0) here — single wait per block

    // ---- store: 1024 16B-chunks (hw,cg), 2 iters x 512 threads.
    // lanes: cg = t&15 (contig 256B global runs), hw group (t>>4).
    u16* dst = ft + ((size_t)b * HW + hw0) * CH + chalf * 128;
    #pragma unroll
    for (int it = 0; it < 2; ++it) {
        int cg = t & 15;                // c = 8cg .. 8cg+7
        int hw = it * 32 + (t >> 4);    // [0,64)
        int q  = (hw + 4 * cg) & 63;    // rot(8cg+j) = 4cg for j<8
        u32 o[4];
        #pragma unroll
        for (int d = 0; d < 4; ++d) {
            int c0 = 8 * cg + 2 * d;
            float va = lf[(size_t)c0 * 64 + q];
            float vb = lf[(size_t)(c0 + 1) * 64 + q];
            o[d] = ((u32)f32_to_bf16_rne(vb) << 16) | (u32)f32_to_bf16_rne(va);
        }
        *(ui4*)(dst + (size_t)hw * CH + 8 * cg) = *(ui4*)o;
    }
}

// ---------------- Pass 2: gather from NHWC bf16 (row-split waves) -----------
__global__ __launch_bounds__(448) void roi_gather_nhwc(
    const u16* __restrict__ ft,      // [N][H][W][CH] bf16
    const float* __restrict__ rois,  // [K][5]
    const int* __restrict__ perm,    // [K] spatial order
    float* __restrict__ out,         // [K][CH][7][7]
    int H, int W, int K, int chunk, int do_swz)
{
    int bid  = blockIdx.x;
    int slot = do_swz ? (bid & 7) * chunk + (bid >> 3) : bid;
    int k    = perm[slot / 7];
    int q    = slot % 7;             // pooled row ph == q
    int bin0 = q * 7;

    __shared__ float lds[7][CH];     // 7 KB

    int lane = threadIdx.x & 63;
    int w    = threadIdx.x >> 6;     // wave = pw (bin col), 0..6
    int half = lane >> 5;            // 0: y0 row, 1: y1 row
    int lc   = lane & 31;            // channel group: ch 8*lc .. 8*lc+7

    const float* rp = rois + (size_t)k * 5;
    int   b   = (int)rp[0];
    float rx1 = rp[1] * SCALE - 0.5f;
    float ry1 = rp[2] * SCALE - 0.5f;
    float rx2 = rp[3] * SCALE - 0.5f;
    float ry2 = rp[4] * SCALE - 0.5f;
    float bin_h = (ry2 - ry1) * (1.0f / POOL_H);
    float bin_w = (rx2 - rx1) * (1.0f / POOL_W);

    const u16* fbase = ft + (size_t)b * H * W * CH + lc * 8;

    int ph = q;
    int pw = w;

    float acc[8];
    #pragma unroll
    for (int j = 0; j < 8; ++j) acc[j] = 0.0f;

    #pragma unroll
    for (int iy = 0; iy < SR; ++iy) {
        float y = ry1 + ((float)ph + ((float)iy + 0.5f) * (1.0f / SR)) * bin_h;
        bool vy = (y > -1.0f) && (y < (float)H);
        float yc = fminf(fmaxf(y, 0.0f), (float)(H - 1));
        int   y0 = (int)yc;
        int   y1 = min(y0 + 1, H - 1);
        float ly = yc - (float)y0;
        float hy = 1.0f - ly;
        int   ysel = half ? y1 : y0;       // per-lane row select
        float wrow = half ? ly : hy;       // per-lane row weight
        #pragma unroll
        for (int ix = 0; ix < SR; ++ix) {
            float x = rx1 + ((float)pw + ((float)ix + 0.5f) * (1.0f / SR)) * bin_w;
            bool vx = (x > -1.0f) && (x < (float)W);
            if (!(vy && vx)) continue;     // wave-uniform branch
            float xc = fminf(fmaxf(x, 0.0f), (float)(W - 1));
            int   x0 = (int)xc;
            int   x1 = min(x0 + 1, W - 1);
            float lx = xc - (float)x0;

            const u16* p0 = fbase + (size_t)(ysel * W + x0) * CH;
            ui4 A = *(const ui4*)p0;                               // (row, x0) 8ch
            ui4 B = *(const ui4*)(p0 + (size_t)(x1 - x0) * CH);    // (row, x1) 8ch

            #pragma unroll
            for (int j = 0; j < 4; ++j) {
                float a0 = bf16lo(A[j]), a1 = bf16hi(A[j]);
                float b0 = bf16lo(B[j]), b1 = bf16hi(B[j]);
                float r0 = a0 + lx * (b0 - a0);
                float r1 = a1 + lx * (b1 - a1);
                acc[2 * j]     += wrow * r0;
                acc[2 * j + 1] += wrow * r1;
            }
        }
    }

    #pragma unroll
    for (int j = 0; j < 8; ++j)
        acc[j] = (acc[j] + __shfl_xor(acc[j], 32, 64)) * 0.25f;

    if (half == 0) {
        f4 lo = { acc[0], acc[1], acc[2], acc[3] };
        f4 hi = { acc[4], acc[5], acc[6], acc[7] };
        *(f4*)&lds[w][lc * 8]     = lo;
        *(f4*)&lds[w][lc * 8 + 4] = hi;
    }
    __syncthreads();

    float* ob = out + (size_t)k * CH * BINS + bin0;
    for (int id = (int)threadIdx.x; id < 7 * CH; id += 448) {
        int c  = id / 7;
        int lb = id % 7;
        ob[(size_t)c * BINS + lb] = lds[lb][c];
    }
}

// ---------------- Fallback (round-3 kernel) if ws too small -----------------
#define NC 2
#define NXCD 8
__global__ __launch_bounds__(256) void roi_align_fallback(
    const float* __restrict__ feat, const float* __restrict__ rois,
    float* __restrict__ out, int C, int H, int W, int K,
    int blocks_per_slice, int slices_per_xcd)
{
    int wgid  = blockIdx.x;
    int g     = wgid % NXCD;
    int r     = wgid / NXCD;
    int slice = g * slices_per_xcd + r / blocks_per_slice;
    int j     = r % blocks_per_slice;
    int tid = j * (int)blockDim.x + (int)threadIdx.x;
    int k   = tid / BINS;
    int bin = tid % BINS;
    if (k >= K) return;
    int pw = bin % POOL_W, ph = bin / POOL_W, c2 = slice;

    const float* rp = rois + (size_t)k * 5;
    int b = (int)rp[0];
    float rx1 = rp[1]*SCALE-0.5f, ry1 = rp[2]*SCALE-0.5f;
    float rx2 = rp[3]*SCALE-0.5f, ry2 = rp[4]*SCALE-0.5f;
    float bin_h = (ry2-ry1)*(1.0f/POOL_H), bin_w = (rx2-rx1)*(1.0f/POOL_W);

    int yr0[SR], yr1[SR]; float ly[SR], hy[SR]; bool vy[SR];
    #pragma unroll
    for (int iy = 0; iy < SR; ++iy) {
        float y = ry1 + ((float)ph + ((float)iy+0.5f)*(1.0f/SR))*bin_h;
        vy[iy] = (y > -1.0f) && (y < (float)H);
        float yc = fminf(fmaxf(y, 0.0f), (float)(H-1));
        int y0 = (int)yc; yr0[iy]=y0; yr1[iy]=min(y0+1,H-1);
        ly[iy]=yc-(float)y0; hy[iy]=1.0f-ly[iy];
    }
    int xl[SR]; float lx[SR]; bool vx[SR], xhi[SR];
    #pragma unroll
    for (int ix = 0; ix < SR; ++ix) {
        float x = rx1 + ((float)pw + ((float)ix+0.5f)*(1.0f/SR))*bin_w;
        vx[ix] = (x > -1.0f) && (x < (float)W);
        float xc = fminf(fmaxf(x, 0.0f), (float)(W-1));
        int x0 = (int)xc; int xload = min(x0, W-2);
        xl[ix]=xload; xhi[ix]=(x0>xload); lx[ix]=xc-(float)x0;
    }
    const size_t HW = (size_t)H*W;
    const float* fmap = feat + ((size_t)b*C + (size_t)c2*NC)*HW;
    float acc[NC];
    #pragma unroll
    for (int cc=0; cc<NC; ++cc) acc[cc]=0.0f;
    #pragma unroll
    for (int iy=0; iy<SR; ++iy)
      #pragma unroll
      for (int ix=0; ix<SR; ++ix)
        if (vy[iy] && vx[ix]) {
            int off0 = yr0[iy]*W + xl[ix], off1 = yr1[iy]*W + xl[ix];
            #pragma unroll
            for (int cc=0; cc<NC; ++cc) {
                const float* base = fmap + (size_t)cc*HW;
                f2v d0 = *(const uf2*)(base + off0);
                f2v d1 = *(const uf2*)(base + off1);
                float v00 = xhi[ix] ? d0.y : d0.x;
                float v10 = xhi[ix] ? d1.y : d1.x;
                float r0 = v00 + lx[ix]*(d0.y - v00);
                float r1 = v10 + lx[ix]*(d1.y - v10);
                acc[cc] += hy[iy]*r0 + ly[iy]*r1;
            }
        }
    size_t obase = ((size_t)k*C + (size_t)c2*NC)*BINS + bin;
    #pragma unroll
    for (int cc=0; cc<NC; ++cc)
        out[obase + (size_t)cc*BINS] = acc[cc]*(1.0f/(SR*SR));
}

extern "C" void kernel_launch(void* const* d_in, const int* in_sizes, int n_in,
                              void* d_out, int out_size, void* d_ws, size_t ws_size,
                              hipStream_t stream) {
    const float* feat = (const float*)d_in[0];
    const float* rois = (const float*)d_in[1];
    float* out = (float*)d_out;

    const int C = 256, H = 200, W = 200;
    const int HW = H * W;
    const int K = in_sizes[1] / 5;
    const int N = in_sizes[0] / (C * HW);

    size_t nhwc_bytes = (size_t)N * HW * CH * sizeof(u16);   // 82 MB for N=4
    size_t need = nhwc_bytes + (size_t)K * sizeof(int);
    if (ws_size >= need && (HW % 64) == 0 && K <= 1024) {
        u16* ft   = (u16*)d_ws;
        int* perm = (int*)((char*)d_ws + nhwc_bytes);
        const int tiles = HW / 64;                           // 625
        nchw_to_nhwc_bf16<<<N * tiles * 2 + 1, 512, 0, stream>>>(
            feat, ft, rois, perm, HW, tiles, K, H, W);
        int grid  = K * 7;                                   // 7168 for K=1024
        int swz   = (grid % 8) == 0;
        int chunk = grid / 8;
        roi_gather_nhwc<<<grid, 448, 0, stream>>>(
            (const u16*)ft, rois, perm, out, H, W, K, chunk, swz);
    } else {
        const int threads_per_slice = K * BINS;
        const int block = 256;
        const int blocks_per_slice = (threads_per_slice + block - 1) / block;
        const int slices = C / NC;
        const int slices_per_xcd = slices / NXCD;
        const int grid = slices * blocks_per_slice;
        roi_align_fallback<<<grid, block, 0, stream>>>(feat, rois, out, C, H, W, K,
                                                       blocks_per_slice, slices_per_xcd);
    }
}

// Round 11
// 94.558 us; speedup vs baseline: 1.0228x; 1.0228x over previous
//
#include <hip/hip_runtime.h>

#define POOL_H 7
#define POOL_W 7
#define BINS   49
#define SR 2
#define SCALE 0.25f
#define CH 256          // channels (fixed by problem)

typedef unsigned int   u32;
typedef unsigned short u16;
typedef unsigned long long u64;
typedef float f2v __attribute__((ext_vector_type(2)));
typedef f2v uf2 __attribute__((aligned(4)));
typedef float f4  __attribute__((ext_vector_type(4)));
typedef u32  ui4 __attribute__((ext_vector_type(4)));

__device__ __forceinline__ u16 f32_to_bf16_rne(float f) {
    u32 u = __builtin_bit_cast(u32, f);
    u32 r = (u + 0x7FFFu + ((u >> 16) & 1u)) >> 16;
    return (u16)r;
}
__device__ __forceinline__ float bf16lo(u32 u) { return __builtin_bit_cast(float, u << 16); }
__device__ __forceinline__ float bf16hi(u32 u) { return __builtin_bit_cast(float, u & 0xFFFF0000u); }

// ---------------- Pass 1: NCHW f32 -> NHWC bf16 (CONJUGATE transpose) -------
// Previous 3 variants all had STRIDED READS (256-512B at 160KB stride) and
// were pinned at ~2.6-3 TB/s. This flips the strided side to the WRITES:
//  - tile = 64 c x 512 hw: each channel row read as a 2KB sequential stream
//    (16 x 128B-coalesced instrs back-to-back per row) -> page-friendly reads
//  - stores: per hw one 128B chunk (64 ch bf16) = exactly one L2 line, at
//    512B stride. Full-line fire-and-forget stores need no latency budget.
// LDS [64][258] u32 with +c rotation swizzle (phys hwpair = (hp + c) & 255).
__global__ __launch_bounds__(512) void nchw_to_nhwc_bf16(
    const float* __restrict__ feat, u16* __restrict__ ft,
    const float* __restrict__ rois, int* __restrict__ perm,
    int HW, int nwin, int K, int H, int W, int N)
{
    __shared__ u32 lds32[64 * 258];      // 66 KB -> 2 blocks/CU
    int t = threadIdx.x;

    if ((int)blockIdx.x == gridDim.x - 1) {
        // ---- ROI spatial sort (K <= 1024) ----
        __shared__ u64 keys[1024];
        int bd = (int)blockDim.x;
        for (int v = t; v < 1024; v += bd) {
            u64 kv = ~0ull;
            if (v < K) {
                const float* rp = rois + (size_t)v * 5;
                int b = (int)rp[0];
                float cx = 0.5f * (rp[1] + rp[3]) * SCALE;
                float cy = 0.5f * (rp[2] + rp[4]) * SCALE;
                int qx = min(15, max(0, (int)(cx * (16.0f / (float)W))));
                int qy = min(15, max(0, (int)(cy * (16.0f / (float)H))));
                u32 m = 0;
                #pragma unroll
                for (int i = 0; i < 4; ++i)
                    m |= (((qy >> i) & 1u) << (2 * i + 1)) | (((qx >> i) & 1u) << (2 * i));
                u32 key = ((u32)b << 8) | m;
                kv = ((u64)key << 32) | (u32)v;
            }
            keys[v] = kv;
        }
        __syncthreads();
        for (int size = 2; size <= 1024; size <<= 1) {
            for (int stride = size >> 1; stride > 0; stride >>= 1) {
                for (int v = t; v < 1024; v += bd) {
                    int j = v ^ stride;
                    if (j > v) {
                        bool up = ((v & size) == 0);
                        u64 a = keys[v], bb = keys[j];
                        if ((a > bb) == up) { keys[v] = bb; keys[j] = a; }
                    }
                }
                __syncthreads();
            }
        }
        for (int v = t; v < K; v += bd)
            perm[v] = (int)(keys[v] & 0xffffffffu);
        return;
    }

    int bid = blockIdx.x;
    int win = bid / (4 * N);
    int rr  = bid % (4 * N);
    int ct  = rr / N;               // c-tile 0..3 (64 ch each)
    int b   = rr % N;
    int hw0 = win * 512;
    int nhw = min(512, HW - hw0);

    int row = t >> 3;               // 0..63: channel within tile
    int seg = t & 7;

    const float* src = feat + ((size_t)b * CH + (size_t)ct * 64 + row) * HW + hw0;

    // ---- read: 16 chunks of 16B per thread; instr m = 8 rows x 128B
    // coalesced; per row the 16 m-iters stream 2KB sequentially.
    f4 v[16];
    #pragma unroll
    for (int m = 0; m < 16; ++m) {
        int chunk = m * 8 + seg;
        if (chunk * 4 < nhw) v[m] = *(const f4*)(src + chunk * 4);
        else                 v[m] = (f4){0.f, 0.f, 0.f, 0.f};
    }
    // ---- convert + stage (swizzled)
    #pragma unroll
    for (int m = 0; m < 16; ++m) {
        int chunk = m * 8 + seg;
        u32 p0 = ((u32)f32_to_bf16_rne(v[m].y) << 16) | (u32)f32_to_bf16_rne(v[m].x);
        u32 p1 = ((u32)f32_to_bf16_rne(v[m].w) << 16) | (u32)f32_to_bf16_rne(v[m].z);
        int hp = chunk * 2;
        lds32[row * 258 + ((hp     + row) & 255)] = p0;
        lds32[row * 258 + ((hp + 1 + row) & 255)] = p1;
    }
    __syncthreads();

    // ---- store: per hw, thread j writes channels j*8..j*8+7 (16B);
    // 8 threads cover the 128B (64ch) line; wave = 8 hw x 128B at 512B stride.
    u16* dst = ft + ((size_t)b * HW + hw0) * CH + ct * 64;
    int j   = t & 7;
    int hwo = t >> 3;               // 0..63
    #pragma unroll
    for (int i = 0; i < 8; ++i) {
        int hw = i * 64 + hwo;
        if (hw < nhw) {
            int hp = hw >> 1, half = hw & 1;
            u32 o[4];
            #pragma unroll
            for (int d = 0; d < 4; ++d) {
                int c0 = j * 8 + 2 * d;
                u32 a  = lds32[c0       * 258 + ((hp + c0)     & 255)];
                u32 bb = lds32[(c0 + 1) * 258 + ((hp + c0 + 1) & 255)];
                u32 lo = half ? (a  >> 16) : (a  & 0xFFFFu);
                u32 hi = half ? (bb >> 16) : (bb & 0xFFFFu);
                o[d] = (hi << 16) | lo;
            }
            *(ui4*)(dst + (size_t)hw * CH + j * 8) = *(ui4*)o;
        }
    }
}

// ---------------- Pass 2: gather from NHWC bf16 (row-split waves) -----------
__global__ __launch_bounds__(448) void roi_gather_nhwc(
    const u16* __restrict__ ft,      // [N][H][W][CH] bf16
    const float* __restrict__ rois,  // [K][5]
    const int* __restrict__ perm,    // [K] spatial order
    float* __restrict__ out,         // [K][CH][7][7]
    int H, int W, int K, int chunk, int do_swz)
{
    int bid  = blockIdx.x;
    int slot = do_swz ? (bid & 7) * chunk + (bid >> 3) : bid;
    int k    = perm[slot / 7];
    int q    = slot % 7;             // pooled row ph == q
    int bin0 = q * 7;

    __shared__ float lds[7][CH];     // 7 KB

    int lane = threadIdx.x & 63;
    int w    = threadIdx.x >> 6;     // wave = pw (bin col), 0..6
    int half = lane >> 5;            // 0: y0 row, 1: y1 row
    int lc   = lane & 31;            // channel group: ch 8*lc .. 8*lc+7

    const float* rp = rois + (size_t)k * 5;
    int   b   = (int)rp[0];
    float rx1 = rp[1] * SCALE - 0.5f;
    float ry1 = rp[2] * SCALE - 0.5f;
    float rx2 = rp[3] * SCALE - 0.5f;
    float ry2 = rp[4] * SCALE - 0.5f;
    float bin_h = (ry2 - ry1) * (1.0f / POOL_H);
    float bin_w = (rx2 - rx1) * (1.0f / POOL_W);

    const u16* fbase = ft + (size_t)b * H * W * CH + lc * 8;

    int ph = q;
    int pw = w;

    float acc[8];
    #pragma unroll
    for (int j = 0; j < 8; ++j) acc[j] = 0.0f;

    #pragma unroll
    for (int iy = 0; iy < SR; ++iy) {
        float y = ry1 + ((float)ph + ((float)iy + 0.5f) * (1.0f / SR)) * bin_h;
        bool vy = (y > -1.0f) && (y < (float)H);
        float yc = fminf(fmaxf(y, 0.0f), (float)(H - 1));
        int   y0 = (int)yc;
        int   y1 = min(y0 + 1, H - 1);
        float ly = yc - (float)y0;
        float hy = 1.0f - ly;
        int   ysel = half ? y1 : y0;       // per-lane row select
        float wrow = half ? ly : hy;       // per-lane row weight
        #pragma unroll
        for (int ix = 0; ix < SR; ++ix) {
            float x = rx1 + ((float)pw + ((float)ix + 0.5f) * (1.0f / SR)) * bin_w;
            bool vx = (x > -1.0f) && (x < (float)W);
            if (!(vy && vx)) continue;     // wave-uniform branch
            float xc = fminf(fmaxf(x, 0.0f), (float)(W - 1));
            int   x0 = (int)xc;
            int   x1 = min(x0 + 1, W - 1);
            float lx = xc - (float)x0;

            const u16* p0 = fbase + (size_t)(ysel * W + x0) * CH;
            ui4 A = *(const ui4*)p0;                               // (row, x0) 8ch
            ui4 B = *(const ui4*)(p0 + (size_t)(x1 - x0) * CH);    // (row, x1) 8ch

            #pragma unroll
            for (int j = 0; j < 4; ++j) {
                float a0 = bf16lo(A[j]), a1 = bf16hi(A[j]);
                float b0 = bf16lo(B[j]), b1 = bf16hi(B[j]);
                float r0 = a0 + lx * (b0 - a0);
                float r1 = a1 + lx * (b1 - a1);
                acc[2 * j]     += wrow * r0;
                acc[2 * j + 1] += wrow * r1;
            }
        }
    }

    #pragma unroll
    for (int j = 0; j < 8; ++j)
        acc[j] = (acc[j] + __shfl_xor(acc[j], 32, 64)) * 0.25f;

    if (half == 0) {
        f4 lo = { acc[0], acc[1], acc[2], acc[3] };
        f4 hi = { acc[4], acc[5], acc[6], acc[7] };
        *(f4*)&lds[w][lc * 8]     = lo;
        *(f4*)&lds[w][lc * 8 + 4] = hi;
    }
    __syncthreads();

    float* ob = out + (size_t)k * CH * BINS + bin0;
    for (int id = (int)threadIdx.x; id < 7 * CH; id += 448) {
        int c  = id / 7;
        int lb = id % 7;
        ob[(size_t)c * BINS + lb] = lds[lb][c];
    }
}

// ---------------- Fallback (round-3 kernel) if ws too small -----------------
#define NC 2
#define NXCD 8
__global__ __launch_bounds__(256) void roi_align_fallback(
    const float* __restrict__ feat, const float* __restrict__ rois,
    float* __restrict__ out, int C, int H, int W, int K,
    int blocks_per_slice, int slices_per_xcd)
{
    int wgid  = blockIdx.x;
    int g     = wgid % NXCD;
    int r     = wgid / NXCD;
    int slice = g * slices_per_xcd + r / blocks_per_slice;
    int j     = r % blocks_per_slice;
    int tid = j * (int)blockDim.x + (int)threadIdx.x;
    int k   = tid / BINS;
    int bin = tid % BINS;
    if (k >= K) return;
    int pw = bin % POOL_W, ph = bin / POOL_W, c2 = slice;

    const float* rp = rois + (size_t)k * 5;
    int b = (int)rp[0];
    float rx1 = rp[1]*SCALE-0.5f, ry1 = rp[2]*SCALE-0.5f;
    float rx2 = rp[3]*SCALE-0.5f, ry2 = rp[4]*SCALE-0.5f;
    float bin_h = (ry2-ry1)*(1.0f/POOL_H), bin_w = (rx2-rx1)*(1.0f/POOL_W);

    int yr0[SR], yr1[SR]; float ly[SR], hy[SR]; bool vy[SR];
    #pragma unroll
    for (int iy = 0; iy < SR; ++iy) {
        float y = ry1 + ((float)ph + ((float)iy+0.5f)*(1.0f/SR))*bin_h;
        vy[iy] = (y > -1.0f) && (y < (float)H);
        float yc = fminf(fmaxf(y, 0.0f), (float)(H-1));
        int y0 = (int)yc; yr0[iy]=y0; yr1[iy]=min(y0+1,H-1);
        ly[iy]=yc-(float)y0; hy[iy]=1.0f-ly[iy];
    }
    int xl[SR]; float lx[SR]; bool vx[SR], xhi[SR];
    #pragma unroll
    for (int ix = 0; ix < SR; ++ix) {
        float x = rx1 + ((float)pw + ((float)ix+0.5f)*(1.0f/SR))*bin_w;
        vx[ix] = (x > -1.0f) && (x < (float)W);
        float xc = fminf(fmaxf(x, 0.0f), (float)(W-1));
        int x0 = (int)xc; int xload = min(x0, W-2);
        xl[ix]=xload; xhi[ix]=(x0>xload); lx[ix]=xc-(float)x0;
    }
    const size_t HW = (size_t)H*W;
    const float* fmap = feat + ((size_t)b*C + (size_t)c2*NC)*HW;
    float acc[NC];
    #pragma unroll
    for (int cc=0; cc<NC; ++cc) acc[cc]=0.0f;
    #pragma unroll
    for (int iy=0; iy<SR; ++iy)
      #pragma unroll
      for (int ix=0; ix<SR; ++ix)
        if (vy[iy] && vx[ix]) {
            int off0 = yr0[iy]*W + xl[ix], off1 = yr1[iy]*W + xl[ix];
            #pragma unroll
            for (int cc=0; cc<NC; ++cc) {
                const float* base = fmap + (size_t)cc*HW;
                f2v d0 = *(const uf2*)(base + off0);
                f2v d1 = *(const uf2*)(base + off1);
                float v00 = xhi[ix] ? d0.y : d0.x;
                float v10 = xhi[ix] ? d1.y : d1.x;
                float r0 = v00 + lx[ix]*(d0.y - v00);
                float r1 = v10 + lx[ix]*(d1.y - v10);
                acc[cc] += hy[iy]*r0 + ly[iy]*r1;
            }
        }
    size_t obase = ((size_t)k*C + (size_t)c2*NC)*BINS + bin;
    #pragma unroll
    for (int cc=0; cc<NC; ++cc)
        out[obase + (size_t)cc*BINS] = acc[cc]*(1.0f/(SR*SR));
}

extern "C" void kernel_launch(void* const* d_in, const int* in_sizes, int n_in,
                              void* d_out, int out_size, void* d_ws, size_t ws_size,
                              hipStream_t stream) {
    const float* feat = (const float*)d_in[0];
    const float* rois = (const float*)d_in[1];
    float* out = (float*)d_out;

    const int C = 256, H = 200, W = 200;
    const int HW = H * W;
    const int K = in_sizes[1] / 5;
    const int N = in_sizes[0] / (C * HW);

    size_t nhwc_bytes = (size_t)N * HW * CH * sizeof(u16);   // 82 MB for N=4
    size_t need = nhwc_bytes + (size_t)K * sizeof(int);
    if (ws_size >= need && K <= 1024) {
        u16* ft   = (u16*)d_ws;
        int* perm = (int*)((char*)d_ws + nhwc_bytes);
        const int nwin = (HW + 511) / 512;                   // 79
        nchw_to_nhwc_bf16<<<nwin * 4 * N + 1, 512, 0, stream>>>(
            feat, ft, rois, perm, HW, nwin, K, H, W, N);
        int grid  = K * 7;                                   // 7168 for K=1024
        int swz   = (grid % 8) == 0;
        int chunk = grid / 8;
        roi_gather_nhwc<<<grid, 448, 0, stream>>>(
            (const u16*)ft, rois, perm, out, H, W, K, chunk, swz);
    } else {
        const int threads_per_slice = K * BINS;
        const int block = 256;
        const int blocks_per_slice = (threads_per_slice + block - 1) / block;
        const int slices = C / NC;
        const int slices_per_xcd = slices / NXCD;
        const int grid = slices * blocks_per_slice;
        roi_align_fallback<<<grid, block, 0, stream>>>(feat, rois, out, C, H, W, K,
                                                       blocks_per_slice, slices_per_xcd);
    }
}